// Round 12
// baseline (261.538 us; speedup 1.0000x reference)
//
#include <hip/hip_runtime.h>
#include <math.h>

// Problem constants: B=2, L=2048, E=1024, H=16, D=64
#define LQ 2048
#define EQ 1024
#define M_ROWS 4096
#define BH 32

typedef _Float16 f16x8 __attribute__((ext_vector_type(8)));
typedef _Float16 f16x4 __attribute__((ext_vector_type(4)));
typedef _Float16 f16x2 __attribute__((ext_vector_type(2)));
typedef float f32x4 __attribute__((ext_vector_type(4)));
typedef float f32x16 __attribute__((ext_vector_type(16)));

// 1/sqrt(64) * log2(e) -> softmax in exp2 domain (applied to combined q)
#define QSCALE 0.1803368801111204f
// defer-max threshold in exp2 domain: P bounded by 2^8 = 256 (fine in f16)
#define DEFER_THR 8.0f

__device__ __forceinline__ void async_ld16(const _Float16* g, _Float16* l) {
  __builtin_amdgcn_global_load_lds(
      (const __attribute__((address_space(1))) unsigned int*)g,
      (__attribute__((address_space(3))) unsigned int*)l, 16, 0, 0);
}

// ---------------------------------------------------------------------------
// Prep (1 launch): blocks [0,4096) convert xt,xs fp32->fp16;
// blocks [4096,7168) transpose W fp32[k][n] -> WT fp16[n][k] in 32k x 64c
// tiles, float2 loads, f16x2 stores (64B contiguous per 16-lane group).
// ---------------------------------------------------------------------------
__global__ __launch_bounds__(256) void prep(
    const float* __restrict__ xt, const float* __restrict__ xs,
    const float* __restrict__ Wt, const float* __restrict__ Ws,
    const float* __restrict__ Wc,
    _Float16* __restrict__ xt16, _Float16* __restrict__ xs16,
    _Float16* __restrict__ WtT, _Float16* __restrict__ WsT,
    _Float16* __restrict__ WcT) {
  int gb = blockIdx.x;
  if (gb < 4096) {
    int i = gb * 256 + threadIdx.x;
    const float* s; _Float16* d; size_t off;
    if (i < 524288) { s = xt; d = xt16; off = (size_t)i * 8; }
    else            { s = xs; d = xs16; off = (size_t)(i - 524288) * 8; }
    float4 a = *(const float4*)&s[off];
    float4 b = *(const float4*)&s[off + 4];
    f16x8 h;
    h[0] = (_Float16)a.x; h[1] = (_Float16)a.y; h[2] = (_Float16)a.z; h[3] = (_Float16)a.w;
    h[4] = (_Float16)b.x; h[5] = (_Float16)b.y; h[6] = (_Float16)b.z; h[7] = (_Float16)b.w;
    *(f16x8*)&d[off] = h;
  } else {
    __shared__ float T[32][65];
    int tb = gb - 4096;                 // 0..3071
    int c0 = (tb % 96) * 64;            // global col tile over 6144
    int k0 = (tb / 96) * 32;            // k tile over 1024
    const float* W; _Float16* D; int Nw, cl;
    if (c0 < 3072)      { W = Wt; D = WtT; Nw = 3072; cl = c0; }
    else if (c0 < 5120) { W = Ws; D = WsT; Nw = 2048; cl = c0 - 3072; }
    else                { W = Wc; D = WcT; Nw = 1024; cl = c0 - 5120; }
    const int tid = threadIdx.x;
    // Load: 32 rows x 64 cols = 1024 float2; 4 per thread
#pragma unroll
    for (int p = 0; p < 4; ++p) {
      int idx = tid + p * 256;
      int row = idx >> 5;               // 0..31
      int c2 = (idx & 31) * 2;          // 0..62
      float2 v = *(const float2*)&W[(size_t)(k0 + row) * Nw + cl + c2];
      T[row][c2] = v.x;
      T[row][c2 + 1] = v.y;
    }
    __syncthreads();
    // Store: 64 cols x 16 k-pairs = 1024 f16x2; 4 per thread
#pragma unroll
    for (int p = 0; p < 4; ++p) {
      int idx = tid + p * 256;
      int col = idx >> 4;               // 0..63
      int k2 = (idx & 15) * 2;          // 0..30
      f16x2 h2;
      h2[0] = (_Float16)T[k2][col];
      h2[1] = (_Float16)T[k2 + 1][col];
      *(f16x2*)&D[(size_t)(cl + col) * 1024 + k0 + k2] = h2;
    }
  }
}

// ---------------------------------------------------------------------------
// Merged projection GEMM v3: 128x128 tile, BK=32 dbuf pipeline, swapped MFMA
// operands, XCD-chunked block swizzle (1280 wgs, 160/XCD -> A-panel L2
// reuse), and an LDS-transpose epilogue: acc -> swizzled 128x128 f16 LDS
// tile -> full-cacheline 16B/lane contiguous global stores. Grid (16, 80).
// ---------------------------------------------------------------------------
__global__ __launch_bounds__(256, 3) void proj_gemm(
    const _Float16* __restrict__ xt16, const _Float16* __restrict__ xs16,
    const _Float16* __restrict__ WtT, const _Float16* __restrict__ WsT,
    const float* __restrict__ bt, const float* __restrict__ bs,
    _Float16* __restrict__ q16, _Float16* __restrict__ k16,
    _Float16* __restrict__ v16) {
  __shared__ _Float16 LS[128 * 128];   // 32KB: 4x (128*32) staging, then epilogue tile
  _Float16* Al0 = LS;
  _Float16* Bl0 = LS + 4096;
  _Float16* Al1 = LS + 8192;
  _Float16* Bl1 = LS + 12288;

  const int tid = threadIdx.x;
  const int w = tid >> 6;
  const int lane = tid & 63;
  const int quad = lane >> 4;
  const int l15 = lane & 15;
  const int wm = w >> 1, wn = w & 1;

  // XCD-chunked bijective swizzle over 1280 wgs (1280 % 8 == 0, 160/XCD)
  const int wg = blockIdx.y * 16 + blockIdx.x;
  const int swz = (wg & 7) * 160 + (wg >> 3);
  const int bx = swz & 15;
  const int by = swz >> 4;
  const int n0 = bx * 128;

  const _Float16* Ab;
  const _Float16* Bb;
  const float* bias;
  int m0, bsel = 0, branch;
  if (by < 32) {            // t-QK
    branch = 0; Ab = xt16; Bb = WtT; bias = bt; m0 = by * 128;
  } else if (by < 48) {     // V^T
    branch = 1;
    int by2 = by - 32;
    bsel = by2 >> 3;
    m0 = (by2 & 7) * 128;
    Ab = WtT + (size_t)2048 * 1024;
    Bb = xt16 + (size_t)bsel * 2048 * 1024;
    bias = bt;
  } else {                  // s-QK
    branch = 2; Ab = xs16; Bb = WsT; bias = bs; m0 = (by - 48) * 128;
  }

  const int srow = lane >> 2;
  const int schunk = ((lane & 3) ^ ((lane >> 3) & 3)) * 8;
  const int key = (l15 >> 1) & 3;

  f32x4 acc[4][4];
#pragma unroll
  for (int mb = 0; mb < 4; ++mb)
#pragma unroll
    for (int nb = 0; nb < 4; ++nb) acc[mb][nb] = (f32x4){0.f, 0.f, 0.f, 0.f};

  auto dma = [&](int kt, _Float16* Al, _Float16* Bl) {
#pragma unroll
    for (int i = 0; i < 2; ++i) {
      int rt = w * 32 + i * 16;
      async_ld16(&Ab[(size_t)(m0 + rt + srow) * 1024 + kt + schunk], &Al[rt * 32]);
      async_ld16(&Bb[(size_t)(n0 + rt + srow) * 1024 + kt + schunk], &Bl[rt * 32]);
    }
  };

  auto comp = [&](const _Float16* Al, const _Float16* Bl) {
    f16x8 af[4], bf[4];
    const int pc = (quad ^ key) * 8;
#pragma unroll
    for (int mb = 0; mb < 4; ++mb)
      af[mb] = *(const f16x8*)&Al[(wm * 64 + mb * 16 + l15) * 32 + pc];
#pragma unroll
    for (int nb = 0; nb < 4; ++nb)
      bf[nb] = *(const f16x8*)&Bl[(wn * 64 + nb * 16 + l15) * 32 + pc];
    // swapped operands: reg/quad dim -> N (bf rows), lane dim -> M (af rows)
#pragma unroll
    for (int mb = 0; mb < 4; ++mb)
#pragma unroll
      for (int nb = 0; nb < 4; ++nb)
        acc[mb][nb] = __builtin_amdgcn_mfma_f32_16x16x32_f16(bf[nb], af[mb], acc[mb][nb], 0, 0, 0);
  };

  dma(0, Al0, Bl0);
  for (int kt = 0; kt < 1024; kt += 64) {
    __syncthreads();
    dma(kt + 32, Al1, Bl1);
    comp(Al0, Bl0);
    __syncthreads();
    if (kt + 64 < 1024) dma(kt + 64, Al0, Bl0);
    comp(Al1, Bl1);
  }

  // ---- Epilogue: acc -> swizzled LDS tile -> full-line global stores ----
  __syncthreads();   // all waves done reading staging buffers
#pragma unroll
  for (int mb = 0; mb < 4; ++mb) {
    const int rowL = wm * 64 + mb * 16 + l15;            // local row 0..127
    const int rx = (rowL & 7) << 3;                      // 8-half chunk XOR
    float rbias = 0.f;
    if (branch == 1) rbias = bias[2048 + m0 + rowL];
#pragma unroll
    for (int nb = 0; nb < 4; ++nb) {
      const int colL = wn * 64 + nb * 16 + quad * 4;     // local col 0..127
      f16x4 o4;
      if (branch == 1) {
#pragma unroll
        for (int r = 0; r < 4; ++r) o4[r] = (_Float16)(acc[mb][nb][r] + rbias);
      } else {
        const float4 bv4 = *(const float4*)&bias[n0 + colL];
        o4[0] = (_Float16)(acc[mb][nb][0] + bv4.x);
        o4[1] = (_Float16)(acc[mb][nb][1] + bv4.y);
        o4[2] = (_Float16)(acc[mb][nb][2] + bv4.z);
        o4[3] = (_Float16)(acc[mb][nb][3] + bv4.w);
      }
      *(f16x4*)&LS[rowL * 128 + (colL ^ rx)] = o4;
    }
  }
  __syncthreads();

  // Write-out: 16 threads per row cover 128 cols; 8 lanes x 16B = 128B
  // contiguous along the innermost (dd / key) axis -> full-line stores.
  const int g = tid & 15;
  const int c8 = g * 8;
#pragma unroll
  for (int p = 0; p < 8; ++p) {
    const int r = p * 16 + (tid >> 4);                   // 0..127
    f16x8 v8 = *(const f16x8*)&LS[r * 128 + (c8 ^ ((r & 7) << 3))];
    if (branch == 1) {
      *(f16x8*)&v16[(size_t)(bsel * 1024 + m0 + r) * 2048 + n0 + c8] = v8;
    } else {
      const int grow = m0 + r;
      const int col = n0 + c8;
      const int bb = grow >> 11, ll = grow & 2047;
      const int which = col >> 10, e = col & 1023;
      const int hh = e >> 6, dd = e & 63;
      _Float16* dst = which ? k16 : q16;
      const int off = (branch == 0) ? 0 : 64;
      *(f16x8*)&dst[((size_t)(bb * 16 + hh) * 2048 + ll) * 128 + off + dd] = v8;
    }
  }
}

// ---------------------------------------------------------------------------
// c_proj GEMM: 128x64 tiles, grid (16,32), dbuf BK=32, launch_bounds(256,3).
// MFMA operands swapped -> float4 vectorized epilogue.
// ---------------------------------------------------------------------------
__global__ __launch_bounds__(256, 3) void cproj_gemm(
    const _Float16* __restrict__ A, const _Float16* __restrict__ Bm,
    const float* __restrict__ bias, float* __restrict__ outf) {
  __shared__ _Float16 Al0[128 * 32];
  __shared__ _Float16 Bl0[64 * 32];
  __shared__ _Float16 Al1[128 * 32];
  __shared__ _Float16 Bl1[64 * 32];

  const int tid = threadIdx.x;
  const int w = tid >> 6;
  const int lane = tid & 63;
  const int quad = lane >> 4;
  const int l15 = lane & 15;
  const int wm = w >> 1, wn = w & 1;
  const int m0 = blockIdx.y * 128;
  const int n0 = blockIdx.x * 64;

  const int srow = lane >> 2;
  const int schunk = ((lane & 3) ^ ((lane >> 3) & 3)) * 8;

  f32x4 acc[4][2];
#pragma unroll
  for (int mb = 0; mb < 4; ++mb)
#pragma unroll
    for (int nb = 0; nb < 2; ++nb) acc[mb][nb] = (f32x4){0.f, 0.f, 0.f, 0.f};

  const int key = (l15 >> 1) & 3;

  auto dma = [&](int kt, _Float16* Al, _Float16* Bl) {
#pragma unroll
    for (int i = 0; i < 2; ++i) {
      int rt = w * 32 + i * 16;
      async_ld16(&A[(size_t)(m0 + rt + srow) * 1024 + kt + schunk], &Al[rt * 32]);
    }
    int rtb = w * 16;
    async_ld16(&Bm[(size_t)(n0 + rtb + srow) * 1024 + kt + schunk], &Bl[rtb * 32]);
  };

  auto comp = [&](const _Float16* Al, const _Float16* Bl) {
    f16x8 af[4], bf[2];
    const int pc = (quad ^ key) * 8;
#pragma unroll
    for (int mb = 0; mb < 4; ++mb)
      af[mb] = *(const f16x8*)&Al[(wm * 64 + mb * 16 + l15) * 32 + pc];
#pragma unroll
    for (int nb = 0; nb < 2; ++nb)
      bf[nb] = *(const f16x8*)&Bl[(wn * 32 + nb * 16 + l15) * 32 + pc];
    // swapped operands: reg/quad dim -> N, lane dim -> M
#pragma unroll
    for (int mb = 0; mb < 4; ++mb)
#pragma unroll
      for (int nb = 0; nb < 2; ++nb)
        acc[mb][nb] = __builtin_amdgcn_mfma_f32_16x16x32_f16(bf[nb], af[mb], acc[mb][nb], 0, 0, 0);
  };

  dma(0, Al0, Bl0);
  for (int kt = 0; kt < 1024; kt += 64) {
    __syncthreads();
    dma(kt + 32, Al1, Bl1);
    comp(Al0, Bl0);
    __syncthreads();
    if (kt + 64 < 1024) dma(kt + 64, Al0, Bl0);
    comp(Al1, Bl1);
  }

#pragma unroll
  for (int nb = 0; nb < 2; ++nb) {
    const int col0 = n0 + wn * 32 + nb * 16 + quad * 4;
    const float4 bv4 = *(const float4*)&bias[col0];
#pragma unroll
    for (int mb = 0; mb < 4; ++mb) {
      int row = m0 + wm * 64 + mb * 16 + l15;
      float4 o4;
      o4.x = acc[mb][nb][0] + bv4.x;
      o4.y = acc[mb][nb][1] + bv4.y;
      o4.z = acc[mb][nb][2] + bv4.z;
      o4.w = acc[mb][nb][3] + bv4.w;
      *(float4*)&outf[(size_t)row * 1024 + col0] = o4;
    }
  }
}

// ---------------------------------------------------------------------------
// MFMA flash attention v11: v8's VERIFIED numerics (max-tracking + defer-max,
// static-slot T15 pipeline) restored after the no-max variants (v9b/v10)
// failed identically at 1.4e-2 -- no-max is condemned; cvt_pkrtz exonerated
// (v10 failed without it). v11 keeps only the separable cheap wins:
//  1. cvt_pkrtz pack (16 ops replace 32 casts + 16 ORs; RTZ bias << headroom)
//  2. tree fmax reduce (same result, dep depth 32 -> 5)
//  3. deferred cross-half l-reduce (exactly equal: alpha is row-uniform)
// Everything else byte-identical to v8.
// ---------------------------------------------------------------------------
__global__ __launch_bounds__(256, 2) void flash_attn_mfma(
    const _Float16* __restrict__ qcat, const _Float16* __restrict__ kcat,
    const _Float16* __restrict__ vT, _Float16* __restrict__ y,
    const float* __restrict__ lam_ts, const float* __restrict__ lam_st,
    const float* __restrict__ lam_ss) {
  const int bh = blockIdx.y;
  const int qt0 = blockIdx.x * 128;
  const int b = bh >> 4, h = bh & 15;
  const _Float16* Qg = qcat + (size_t)bh * LQ * 128;
  const _Float16* Kg = kcat + (size_t)bh * LQ * 128;
  const _Float16* Vg = vT + (size_t)bh * 64 * LQ;     // [dim][key]

  __shared__ _Float16 K0s[64 * 128];
  __shared__ _Float16 K1s[64 * 128];
  __shared__ _Float16 V0s[64 * 64];
  __shared__ _Float16 V1s[64 * 64];
  __shared__ _Float16 V2s[64 * 64];
  __shared__ _Float16 V3s[64 * 64];

  const int tid = threadIdx.x;
  const int w = tid >> 6;                    // wave 0..3
  const int lane = tid & 63;
  const int half = lane >> 5;                // 0/1
  const int l31 = lane & 31;

  const float lts = lam_ts[0], lst = lam_st[0], lss = lam_ss[0];

  // Q-combine into B-frags: wave w owns qrows qt0 + w*32 + [0,32)
  f16x8 qf[8];
#pragma unroll
  for (int db = 0; db < 4; ++db) {
    const _Float16* qp = &Qg[(size_t)(qt0 + w * 32 + l31) * 128 + db * 16 + half * 8];
    f16x8 a = *(const f16x8*)qp;          // qt dims
    f16x8 bq = *(const f16x8*)(qp + 64);  // qs dims
#pragma unroll
    for (int e = 0; e < 8; ++e) {
      float fa = (float)a[e], fb = (float)bq[e];
      qf[db][e]     = (_Float16)(QSCALE * (fa + lst * fb));
      qf[db + 4][e] = (_Float16)(QSCALE * (lts * fa + lss * fb));
    }
  }

  float m_i = -INFINITY;
  float l_i = 0.f;                           // own-half partial denominator
  f32x16 O[2];
#pragma unroll
  for (int nt = 0; nt < 2; ++nt)
#pragma unroll
    for (int r = 0; r < 16; ++r) O[nt][r] = 0.f;

  auto dma_k = [&](int t, _Float16* Kd) {
#pragma unroll
    for (int a = 0; a < 4; ++a) {
      int row = w * 16 + a * 4 + (lane >> 4);
      int sc = (lane & 15) ^ (row & 7);
      async_ld16(&Kg[(size_t)(t + row) * 128 + sc * 8], &Kd[(w * 16 + a * 4) * 128]);
    }
  };
  auto dma_v = [&](int t, _Float16* Vd) {
#pragma unroll
    for (int a = 0; a < 2; ++a) {
      int row = w * 16 + a * 8 + (lane >> 3);          // dim
      int sc = (lane & 7) ^ (row & 7);
      async_ld16(&Vg[(size_t)row * LQ + t + sc * 8], &Vd[(w * 16 + a * 8) * 64]);
    }
  };

  // QK^T over one 64-key LDS tile into Sp[0..1] (32 keys each)
  auto qk = [&](const _Float16* Ks, f32x16* Sp) {
#pragma unroll
    for (int kb = 0; kb < 2; ++kb)
#pragma unroll
      for (int r = 0; r < 16; ++r) Sp[kb][r] = 0.f;
#pragma unroll
    for (int db = 0; db < 8; ++db) {
      const int pc = ((db * 2 + half) ^ (lane & 7)) * 8;
      f16x8 af0 = *(const f16x8*)&Ks[l31 * 128 + pc];
      f16x8 af1 = *(const f16x8*)&Ks[(32 + l31) * 128 + pc];
      Sp[0] = __builtin_amdgcn_mfma_f32_32x32x16_f16(af0, qf[db], Sp[0], 0, 0, 0);
      Sp[1] = __builtin_amdgcn_mfma_f32_32x32x16_f16(af1, qf[db], Sp[1], 0, 0, 0);
    }
  };

  // softmax + PV for one 64-key tile (v8 numerics; VALU-trimmed)
  auto softpv = [&](f32x16* S, const _Float16* Vs) {
    // tree-structured max over this lane's 32 S values (depth 5, not 32)
    float tm[16];
#pragma unroll
    for (int r = 0; r < 16; ++r) tm[r] = fmaxf(S[0][r], S[1][r]);
#pragma unroll
    for (int st = 8; st > 0; st >>= 1)
#pragma unroll
      for (int r = 0; r < st; ++r) tm[r] = fmaxf(tm[r], tm[r + st]);
    float mx = fmaxf(tm[0], __shfl_xor(tm[0], 32));

    // defer-max: only rescale when the max grew enough to matter
    if (__any(mx > m_i + DEFER_THR)) {
      float m_new = fmaxf(m_i, mx);
      float alpha = __builtin_amdgcn_exp2f(m_i - m_new);
      l_i *= alpha;
#pragma unroll
      for (int nt = 0; nt < 2; ++nt)
#pragma unroll
        for (int r = 0; r < 16; ++r) O[nt][r] *= alpha;
      m_i = m_new;
    }

    float s = 0.f;
#pragma unroll
    for (int kb = 0; kb < 2; ++kb)
#pragma unroll
      for (int r = 0; r < 16; ++r) {
        float p = __builtin_amdgcn_exp2f(S[kb][r] - m_i);
        S[kb][r] = p;
        s += p;
      }
    l_i += s;            // own-half only; cross-half reduce deferred to epilogue

#pragma unroll
    for (int kb = 0; kb < 2; ++kb) {
      unsigned pu[8];
#pragma unroll
      for (int i = 0; i < 8; ++i)
        pu[i] = __builtin_bit_cast(
            unsigned, __builtin_amdgcn_cvt_pkrtz(S[kb][2 * i], S[kb][2 * i + 1]));
#pragma unroll
      for (int c = 0; c < 2; ++c) {
        unsigned u0 = pu[4 * c + 0], u1 = pu[4 * c + 1];
        unsigned u2 = pu[4 * c + 2], u3 = pu[4 * c + 3];
        asm("v_permlane32_swap_b32 %0, %1" : "+v"(u0), "+v"(u2));
        asm("v_permlane32_swap_b32 %0, %1" : "+v"(u1), "+v"(u3));
        union { unsigned u[4]; f16x8 v; } pb;
        pb.u[0] = u0; pb.u[1] = u1; pb.u[2] = u2; pb.u[3] = u3;
        const int kb2 = kb * 2 + c;            // 16-key granule 0..3
        f16x8 av[2];
#pragma unroll
        for (int nt = 0; nt < 2; ++nt) {
          int dim = nt * 32 + l31;
          int pc = ((kb2 * 2 + half) ^ (dim & 7)) * 8;
          av[nt] = *(const f16x8*)&Vs[dim * 64 + pc];
        }
#pragma unroll
        for (int nt = 0; nt < 2; ++nt)
          O[nt] = __builtin_amdgcn_mfma_f32_32x32x16_f16(av[nt], pb.v, O[nt], 0, 0, 0);
      }
    }
  };

  f32x16 Sa[2], Sb[2];

  // ---- prologue: load tile 0; step 0 (qk tile 0 -> Sb, prefetch tile 1) ----
  dma_k(0, K0s);
  dma_v(0, V0s);
  __syncthreads();
  dma_k(64, K1s);
  dma_v(64, V1s);
  qk(K0s, Sb);

  // ---- steps 1..28: 7 macro-iterations of 4 static steps ----
  // step 4j+1: dK->K0 (tile 4j+2), dV->V2; qk(K1=tile 4j+1)->Sa; softpv(Sb, V0=tile 4j)
  // step 4j+2: dK->K1, dV->V3; qk(K0)->Sb; softpv(Sa, V1)
  // step 4j+3: dK->K0, dV->V0; qk(K1)->Sa; softpv(Sb, V2)
  // step 4j+4: dK->K1, dV->V1; qk(K0)->Sb; softpv(Sa, V3)
  for (int j = 0; j < 7; ++j) {
    const int t = j * 256 + 64;        // global key offset of tile 4j+1
    __syncthreads();
    dma_k(t + 64, K0s);  dma_v(t + 64, V2s);
    qk(K1s, Sa);  softpv(Sb, V0s);
    __syncthreads();
    dma_k(t + 128, K1s); dma_v(t + 128, V3s);
    qk(K0s, Sb);  softpv(Sa, V1s);
    __syncthreads();
    dma_k(t + 192, K0s); dma_v(t + 192, V0s);
    qk(K1s, Sa);  softpv(Sb, V2s);
    __syncthreads();
    dma_k(t + 256, K1s); dma_v(t + 256, V1s);
    qk(K0s, Sb);  softpv(Sa, V3s);
  }

  // ---- step 29: dK(1920 -> K0 = tile 30), dV -> V2; qk(K1 = tile 29); softpv(tile 28, V0)
  __syncthreads();
  dma_k(1920, K0s); dma_v(1920, V2s);
  qk(K1s, Sa);  softpv(Sb, V0s);
  // ---- step 30: dK(1984 -> K1 = tile 31), dV -> V3; qk(K0 = tile 30); softpv(tile 29, V1)
  __syncthreads();
  dma_k(1984, K1s); dma_v(1984, V3s);
  qk(K0s, Sb);  softpv(Sa, V1s);
  // ---- step 31: qk(K1 = tile 31); softpv(tile 30, V2); drain softpv(tile 31, V3)
  __syncthreads();
  qk(K1s, Sa);  softpv(Sb, V2s);
  softpv(Sa, V3s);

  // Final cross-half denominator reduce (deferred from the loop; alpha is
  // row-uniform so own-half scaling is identical on both halves)
  float l_tot = l_i + __shfl_xor(l_i, 32);
  float inv = 1.f / l_tot;
  int qrow = qt0 + w * 32 + l31;
#pragma unroll
  for (int nt = 0; nt < 2; ++nt)
#pragma unroll
    for (int rg = 0; rg < 4; ++rg) {
      f16x4 o4;
#pragma unroll
      for (int i = 0; i < 4; ++i) o4[i] = (_Float16)(O[nt][rg * 4 + i] * inv);
      int dim = nt * 32 + rg * 8 + half * 4;
      *(f16x4*)&y[((size_t)b * LQ + qrow) * EQ + h * 64 + dim] = o4;
    }
}

// ---------------------------------------------------------------------------
extern "C" void kernel_launch(void* const* d_in, const int* in_sizes, int n_in,
                              void* d_out, int out_size, void* d_ws, size_t ws_size,
                              hipStream_t stream) {
  const float* xt = (const float*)d_in[0];
  const float* xs = (const float*)d_in[1];
  const float* Wt = (const float*)d_in[2];
  const float* bt = (const float*)d_in[3];
  const float* Ws = (const float*)d_in[4];
  const float* bs = (const float*)d_in[5];
  const float* Wc = (const float*)d_in[6];
  const float* bc = (const float*)d_in[7];
  const float* lam_ts = (const float*)d_in[8];
  const float* lam_st = (const float*)d_in[9];
  const float* lam_ss = (const float*)d_in[10];
  float* out = (float*)d_out;

  _Float16* w16 = (_Float16*)d_ws;
  _Float16* xt16 = w16;                       // 4,194,304
  _Float16* xs16 = xt16 + 4194304;            // 4,194,304
  _Float16* WtT  = xs16 + 4194304;            // 3,145,728
  _Float16* WsT  = WtT + 3145728;             // 2,097,152
  _Float16* WcT  = WsT + 2097152;             // 1,048,576
  _Float16* qcat = WcT + 1048576;             // 8,388,608  [bh][l][128] = [qt|qs]
  _Float16* kcat = qcat + 8388608;            // 8,388,608  [bh][l][128] = [kt|ks]
  _Float16* vbufT = kcat + 8388608;           // 4,194,304  [bh][dim][l]
  _Float16* ybuf = vbufT + 4194304;           // 4,194,304  [b*l][1024]

  prep<<<7168, 256, 0, stream>>>(xt, xs, Wt, Ws, Wc, xt16, xs16, WtT, WsT, WcT);
  proj_gemm<<<dim3(16, 80), 256, 0, stream>>>(
      xt16, xs16, WtT, WsT, bt, bs, qcat, kcat, vbufT);
  flash_attn_mfma<<<dim3(16, 32), 256, 0, stream>>>(
      qcat, kcat, vbufT, ybuf, lam_ts, lam_st, lam_ss);
  cproj_gemm<<<dim3(16, 32), 256, 0, stream>>>(ybuf, WcT, bc, out);
}

// Round 13
// 251.780 us; speedup vs baseline: 1.0388x; 1.0388x over previous
//
#include <hip/hip_runtime.h>
#include <math.h>

// Problem constants: B=2, L=2048, E=1024, H=16, D=64
#define LQ 2048
#define EQ 1024
#define M_ROWS 4096
#define BH 32

typedef _Float16 f16x8 __attribute__((ext_vector_type(8)));
typedef _Float16 f16x4 __attribute__((ext_vector_type(4)));
typedef _Float16 f16x2 __attribute__((ext_vector_type(2)));
typedef float f32x4 __attribute__((ext_vector_type(4)));
typedef float f32x16 __attribute__((ext_vector_type(16)));

// 1/sqrt(64) * log2(e) -> softmax in exp2 domain (applied to combined q)
#define QSCALE 0.1803368801111204f
// defer-max threshold in exp2 domain: P bounded by 2^8 = 256 (fine in f16)
#define DEFER_THR 8.0f

__device__ __forceinline__ void async_ld16(const _Float16* g, _Float16* l) {
  __builtin_amdgcn_global_load_lds(
      (const __attribute__((address_space(1))) unsigned int*)g,
      (__attribute__((address_space(3))) unsigned int*)l, 16, 0, 0);
}

// ---------------------------------------------------------------------------
// Prep (1 launch): blocks [0,4096) convert xt,xs fp32->fp16;
// blocks [4096,7168) transpose W fp32[k][n] -> WT fp16[n][k] in 32k x 64c
// tiles, float2 loads, f16x2 stores (64B contiguous per 16-lane group).
// ---------------------------------------------------------------------------
__global__ __launch_bounds__(256) void prep(
    const float* __restrict__ xt, const float* __restrict__ xs,
    const float* __restrict__ Wt, const float* __restrict__ Ws,
    const float* __restrict__ Wc,
    _Float16* __restrict__ xt16, _Float16* __restrict__ xs16,
    _Float16* __restrict__ WtT, _Float16* __restrict__ WsT,
    _Float16* __restrict__ WcT) {
  int gb = blockIdx.x;
  if (gb < 4096) {
    int i = gb * 256 + threadIdx.x;
    const float* s; _Float16* d; size_t off;
    if (i < 524288) { s = xt; d = xt16; off = (size_t)i * 8; }
    else            { s = xs; d = xs16; off = (size_t)(i - 524288) * 8; }
    float4 a = *(const float4*)&s[off];
    float4 b = *(const float4*)&s[off + 4];
    f16x8 h;
    h[0] = (_Float16)a.x; h[1] = (_Float16)a.y; h[2] = (_Float16)a.z; h[3] = (_Float16)a.w;
    h[4] = (_Float16)b.x; h[5] = (_Float16)b.y; h[6] = (_Float16)b.z; h[7] = (_Float16)b.w;
    *(f16x8*)&d[off] = h;
  } else {
    __shared__ float T[32][65];
    int tb = gb - 4096;                 // 0..3071
    int c0 = (tb % 96) * 64;            // global col tile over 6144
    int k0 = (tb / 96) * 32;            // k tile over 1024
    const float* W; _Float16* D; int Nw, cl;
    if (c0 < 3072)      { W = Wt; D = WtT; Nw = 3072; cl = c0; }
    else if (c0 < 5120) { W = Ws; D = WsT; Nw = 2048; cl = c0 - 3072; }
    else                { W = Wc; D = WcT; Nw = 1024; cl = c0 - 5120; }
    const int tid = threadIdx.x;
    // Load: 32 rows x 64 cols = 1024 float2; 4 per thread
#pragma unroll
    for (int p = 0; p < 4; ++p) {
      int idx = tid + p * 256;
      int row = idx >> 5;               // 0..31
      int c2 = (idx & 31) * 2;          // 0..62
      float2 v = *(const float2*)&W[(size_t)(k0 + row) * Nw + cl + c2];
      T[row][c2] = v.x;
      T[row][c2 + 1] = v.y;
    }
    __syncthreads();
    // Store: 64 cols x 16 k-pairs = 1024 f16x2; 4 per thread
#pragma unroll
    for (int p = 0; p < 4; ++p) {
      int idx = tid + p * 256;
      int col = idx >> 4;               // 0..63
      int k2 = (idx & 15) * 2;          // 0..30
      f16x2 h2;
      h2[0] = (_Float16)T[k2][col];
      h2[1] = (_Float16)T[k2 + 1][col];
      *(f16x2*)&D[(size_t)(cl + col) * 1024 + k0 + k2] = h2;
    }
  }
}

// ---------------------------------------------------------------------------
// Merged projection GEMM v3: 128x128 tile, BK=32 dbuf pipeline, swapped MFMA
// operands, XCD-chunked block swizzle (1280 wgs, 160/XCD -> A-panel L2
// reuse), and an LDS-transpose epilogue: acc -> swizzled 128x128 f16 LDS
// tile -> full-cacheline 16B/lane contiguous global stores. Grid (16, 80).
// ---------------------------------------------------------------------------
__global__ __launch_bounds__(256, 3) void proj_gemm(
    const _Float16* __restrict__ xt16, const _Float16* __restrict__ xs16,
    const _Float16* __restrict__ WtT, const _Float16* __restrict__ WsT,
    const float* __restrict__ bt, const float* __restrict__ bs,
    _Float16* __restrict__ q16, _Float16* __restrict__ k16,
    _Float16* __restrict__ v16) {
  __shared__ _Float16 LS[128 * 128];   // 32KB: 4x (128*32) staging, then epilogue tile
  _Float16* Al0 = LS;
  _Float16* Bl0 = LS + 4096;
  _Float16* Al1 = LS + 8192;
  _Float16* Bl1 = LS + 12288;

  const int tid = threadIdx.x;
  const int w = tid >> 6;
  const int lane = tid & 63;
  const int quad = lane >> 4;
  const int l15 = lane & 15;
  const int wm = w >> 1, wn = w & 1;

  // XCD-chunked bijective swizzle over 1280 wgs (1280 % 8 == 0, 160/XCD)
  const int wg = blockIdx.y * 16 + blockIdx.x;
  const int swz = (wg & 7) * 160 + (wg >> 3);
  const int bx = swz & 15;
  const int by = swz >> 4;
  const int n0 = bx * 128;

  const _Float16* Ab;
  const _Float16* Bb;
  const float* bias;
  int m0, bsel = 0, branch;
  if (by < 32) {            // t-QK
    branch = 0; Ab = xt16; Bb = WtT; bias = bt; m0 = by * 128;
  } else if (by < 48) {     // V^T
    branch = 1;
    int by2 = by - 32;
    bsel = by2 >> 3;
    m0 = (by2 & 7) * 128;
    Ab = WtT + (size_t)2048 * 1024;
    Bb = xt16 + (size_t)bsel * 2048 * 1024;
    bias = bt;
  } else {                  // s-QK
    branch = 2; Ab = xs16; Bb = WsT; bias = bs; m0 = (by - 48) * 128;
  }

  const int srow = lane >> 2;
  const int schunk = ((lane & 3) ^ ((lane >> 3) & 3)) * 8;
  const int key = (l15 >> 1) & 3;

  f32x4 acc[4][4];
#pragma unroll
  for (int mb = 0; mb < 4; ++mb)
#pragma unroll
    for (int nb = 0; nb < 4; ++nb) acc[mb][nb] = (f32x4){0.f, 0.f, 0.f, 0.f};

  auto dma = [&](int kt, _Float16* Al, _Float16* Bl) {
#pragma unroll
    for (int i = 0; i < 2; ++i) {
      int rt = w * 32 + i * 16;
      async_ld16(&Ab[(size_t)(m0 + rt + srow) * 1024 + kt + schunk], &Al[rt * 32]);
      async_ld16(&Bb[(size_t)(n0 + rt + srow) * 1024 + kt + schunk], &Bl[rt * 32]);
    }
  };

  auto comp = [&](const _Float16* Al, const _Float16* Bl) {
    f16x8 af[4], bf[4];
    const int pc = (quad ^ key) * 8;
#pragma unroll
    for (int mb = 0; mb < 4; ++mb)
      af[mb] = *(const f16x8*)&Al[(wm * 64 + mb * 16 + l15) * 32 + pc];
#pragma unroll
    for (int nb = 0; nb < 4; ++nb)
      bf[nb] = *(const f16x8*)&Bl[(wn * 64 + nb * 16 + l15) * 32 + pc];
    // swapped operands: reg/quad dim -> N (bf rows), lane dim -> M (af rows)
#pragma unroll
    for (int mb = 0; mb < 4; ++mb)
#pragma unroll
      for (int nb = 0; nb < 4; ++nb)
        acc[mb][nb] = __builtin_amdgcn_mfma_f32_16x16x32_f16(bf[nb], af[mb], acc[mb][nb], 0, 0, 0);
  };

  dma(0, Al0, Bl0);
  for (int kt = 0; kt < 1024; kt += 64) {
    __syncthreads();
    dma(kt + 32, Al1, Bl1);
    comp(Al0, Bl0);
    __syncthreads();
    if (kt + 64 < 1024) dma(kt + 64, Al0, Bl0);
    comp(Al1, Bl1);
  }

  // ---- Epilogue: acc -> swizzled LDS tile -> full-line global stores ----
  __syncthreads();   // all waves done reading staging buffers
#pragma unroll
  for (int mb = 0; mb < 4; ++mb) {
    const int rowL = wm * 64 + mb * 16 + l15;            // local row 0..127
    const int rx = (rowL & 7) << 3;                      // 8-half chunk XOR
    float rbias = 0.f;
    if (branch == 1) rbias = bias[2048 + m0 + rowL];
#pragma unroll
    for (int nb = 0; nb < 4; ++nb) {
      const int colL = wn * 64 + nb * 16 + quad * 4;     // local col 0..127
      f16x4 o4;
      if (branch == 1) {
#pragma unroll
        for (int r = 0; r < 4; ++r) o4[r] = (_Float16)(acc[mb][nb][r] + rbias);
      } else {
        const float4 bv4 = *(const float4*)&bias[n0 + colL];
        o4[0] = (_Float16)(acc[mb][nb][0] + bv4.x);
        o4[1] = (_Float16)(acc[mb][nb][1] + bv4.y);
        o4[2] = (_Float16)(acc[mb][nb][2] + bv4.z);
        o4[3] = (_Float16)(acc[mb][nb][3] + bv4.w);
      }
      *(f16x4*)&LS[rowL * 128 + (colL ^ rx)] = o4;
    }
  }
  __syncthreads();

  // Write-out: 16 threads per row cover 128 cols; 8 lanes x 16B = 128B
  // contiguous along the innermost (dd / key) axis -> full-line stores.
  const int g = tid & 15;
  const int c8 = g * 8;
#pragma unroll
  for (int p = 0; p < 8; ++p) {
    const int r = p * 16 + (tid >> 4);                   // 0..127
    f16x8 v8 = *(const f16x8*)&LS[r * 128 + (c8 ^ ((r & 7) << 3))];
    if (branch == 1) {
      *(f16x8*)&v16[(size_t)(bsel * 1024 + m0 + r) * 2048 + n0 + c8] = v8;
    } else {
      const int grow = m0 + r;
      const int col = n0 + c8;
      const int bb = grow >> 11, ll = grow & 2047;
      const int which = col >> 10, e = col & 1023;
      const int hh = e >> 6, dd = e & 63;
      _Float16* dst = which ? k16 : q16;
      const int off = (branch == 0) ? 0 : 64;
      *(f16x8*)&dst[((size_t)(bb * 16 + hh) * 2048 + ll) * 128 + off + dd] = v8;
    }
  }
}

// ---------------------------------------------------------------------------
// c_proj GEMM: 128x64 tiles, grid (16,32), dbuf BK=32, launch_bounds(256,3).
// MFMA operands swapped -> float4 vectorized epilogue.
// ---------------------------------------------------------------------------
__global__ __launch_bounds__(256, 3) void cproj_gemm(
    const _Float16* __restrict__ A, const _Float16* __restrict__ Bm,
    const float* __restrict__ bias, float* __restrict__ outf) {
  __shared__ _Float16 Al0[128 * 32];
  __shared__ _Float16 Bl0[64 * 32];
  __shared__ _Float16 Al1[128 * 32];
  __shared__ _Float16 Bl1[64 * 32];

  const int tid = threadIdx.x;
  const int w = tid >> 6;
  const int lane = tid & 63;
  const int quad = lane >> 4;
  const int l15 = lane & 15;
  const int wm = w >> 1, wn = w & 1;
  const int m0 = blockIdx.y * 128;
  const int n0 = blockIdx.x * 64;

  const int srow = lane >> 2;
  const int schunk = ((lane & 3) ^ ((lane >> 3) & 3)) * 8;

  f32x4 acc[4][2];
#pragma unroll
  for (int mb = 0; mb < 4; ++mb)
#pragma unroll
    for (int nb = 0; nb < 2; ++nb) acc[mb][nb] = (f32x4){0.f, 0.f, 0.f, 0.f};

  const int key = (l15 >> 1) & 3;

  auto dma = [&](int kt, _Float16* Al, _Float16* Bl) {
#pragma unroll
    for (int i = 0; i < 2; ++i) {
      int rt = w * 32 + i * 16;
      async_ld16(&A[(size_t)(m0 + rt + srow) * 1024 + kt + schunk], &Al[rt * 32]);
    }
    int rtb = w * 16;
    async_ld16(&Bm[(size_t)(n0 + rtb + srow) * 1024 + kt + schunk], &Bl[rtb * 32]);
  };

  auto comp = [&](const _Float16* Al, const _Float16* Bl) {
    f16x8 af[4], bf[2];
    const int pc = (quad ^ key) * 8;
#pragma unroll
    for (int mb = 0; mb < 4; ++mb)
      af[mb] = *(const f16x8*)&Al[(wm * 64 + mb * 16 + l15) * 32 + pc];
#pragma unroll
    for (int nb = 0; nb < 2; ++nb)
      bf[nb] = *(const f16x8*)&Bl[(wn * 32 + nb * 16 + l15) * 32 + pc];
    // swapped operands: reg/quad dim -> N, lane dim -> M
#pragma unroll
    for (int mb = 0; mb < 4; ++mb)
#pragma unroll
      for (int nb = 0; nb < 2; ++nb)
        acc[mb][nb] = __builtin_amdgcn_mfma_f32_16x16x32_f16(bf[nb], af[mb], acc[mb][nb], 0, 0, 0);
  };

  dma(0, Al0, Bl0);
  for (int kt = 0; kt < 1024; kt += 64) {
    __syncthreads();
    dma(kt + 32, Al1, Bl1);
    comp(Al0, Bl0);
    __syncthreads();
    if (kt + 64 < 1024) dma(kt + 64, Al0, Bl0);
    comp(Al1, Bl1);
  }

#pragma unroll
  for (int nb = 0; nb < 2; ++nb) {
    const int col0 = n0 + wn * 32 + nb * 16 + quad * 4;
    const float4 bv4 = *(const float4*)&bias[col0];
#pragma unroll
    for (int mb = 0; mb < 4; ++mb) {
      int row = m0 + wm * 64 + mb * 16 + l15;
      float4 o4;
      o4.x = acc[mb][nb][0] + bv4.x;
      o4.y = acc[mb][nb][1] + bv4.y;
      o4.z = acc[mb][nb][2] + bv4.z;
      o4.w = acc[mb][nb][3] + bv4.w;
      *(float4*)&outf[(size_t)row * 1024 + col0] = o4;
    }
  }
}

// ---------------------------------------------------------------------------
// MFMA flash attention v8 (RESTORED verbatim — best verified: 67.7us flash,
// 257.5us total, absmax 4.88e-4). T15 2-deep pipeline with fully static slot
// naming; per-64-key steps, two S states (Sa/Sb); K dbuf (K0/K1), V 4-slot
// rotation (V0..V3); one barrier per step. v11's VALU-trims (tree max,
// cvt_pkrtz, deferred l-reduce) REVERTED: they raised VALUBusy 39->44 and
// cost 3.3us — the compiler already fuses the cast-pair pack, and the hand
// tree forced extra register moves. Do not hand-trim this VALU sequence.
// ---------------------------------------------------------------------------
__global__ __launch_bounds__(256, 2) void flash_attn_mfma(
    const _Float16* __restrict__ qcat, const _Float16* __restrict__ kcat,
    const _Float16* __restrict__ vT, _Float16* __restrict__ y,
    const float* __restrict__ lam_ts, const float* __restrict__ lam_st,
    const float* __restrict__ lam_ss) {
  const int bh = blockIdx.y;
  const int qt0 = blockIdx.x * 128;
  const int b = bh >> 4, h = bh & 15;
  const _Float16* Qg = qcat + (size_t)bh * LQ * 128;
  const _Float16* Kg = kcat + (size_t)bh * LQ * 128;
  const _Float16* Vg = vT + (size_t)bh * 64 * LQ;     // [dim][key]

  __shared__ _Float16 K0s[64 * 128];
  __shared__ _Float16 K1s[64 * 128];
  __shared__ _Float16 V0s[64 * 64];
  __shared__ _Float16 V1s[64 * 64];
  __shared__ _Float16 V2s[64 * 64];
  __shared__ _Float16 V3s[64 * 64];

  const int tid = threadIdx.x;
  const int w = tid >> 6;                    // wave 0..3
  const int lane = tid & 63;
  const int half = lane >> 5;                // 0/1
  const int l31 = lane & 31;

  const float lts = lam_ts[0], lst = lam_st[0], lss = lam_ss[0];

  // Q-combine into B-frags: wave w owns qrows qt0 + w*32 + [0,32)
  f16x8 qf[8];
#pragma unroll
  for (int db = 0; db < 4; ++db) {
    const _Float16* qp = &Qg[(size_t)(qt0 + w * 32 + l31) * 128 + db * 16 + half * 8];
    f16x8 a = *(const f16x8*)qp;          // qt dims
    f16x8 bq = *(const f16x8*)(qp + 64);  // qs dims
#pragma unroll
    for (int e = 0; e < 8; ++e) {
      float fa = (float)a[e], fb = (float)bq[e];
      qf[db][e]     = (_Float16)(QSCALE * (fa + lst * fb));
      qf[db + 4][e] = (_Float16)(QSCALE * (lts * fa + lss * fb));
    }
  }

  float m_i = -INFINITY;
  float l_i = 0.f;
  f32x16 O[2];
#pragma unroll
  for (int nt = 0; nt < 2; ++nt)
#pragma unroll
    for (int r = 0; r < 16; ++r) O[nt][r] = 0.f;

  auto dma_k = [&](int t, _Float16* Kd) {
#pragma unroll
    for (int a = 0; a < 4; ++a) {
      int row = w * 16 + a * 4 + (lane >> 4);
      int sc = (lane & 15) ^ (row & 7);
      async_ld16(&Kg[(size_t)(t + row) * 128 + sc * 8], &Kd[(w * 16 + a * 4) * 128]);
    }
  };
  auto dma_v = [&](int t, _Float16* Vd) {
#pragma unroll
    for (int a = 0; a < 2; ++a) {
      int row = w * 16 + a * 8 + (lane >> 3);          // dim
      int sc = (lane & 7) ^ (row & 7);
      async_ld16(&Vg[(size_t)row * LQ + t + sc * 8], &Vd[(w * 16 + a * 8) * 64]);
    }
  };

  // QK^T over one 64-key LDS tile into Sp[0..1] (32 keys each)
  auto qk = [&](const _Float16* Ks, f32x16* Sp) {
#pragma unroll
    for (int kb = 0; kb < 2; ++kb)
#pragma unroll
      for (int r = 0; r < 16; ++r) Sp[kb][r] = 0.f;
#pragma unroll
    for (int db = 0; db < 8; ++db) {
      const int pc = ((db * 2 + half) ^ (lane & 7)) * 8;
      f16x8 af0 = *(const f16x8*)&Ks[l31 * 128 + pc];
      f16x8 af1 = *(const f16x8*)&Ks[(32 + l31) * 128 + pc];
      Sp[0] = __builtin_amdgcn_mfma_f32_32x32x16_f16(af0, qf[db], Sp[0], 0, 0, 0);
      Sp[1] = __builtin_amdgcn_mfma_f32_32x32x16_f16(af1, qf[db], Sp[1], 0, 0, 0);
    }
  };

  // softmax + PV for one 64-key tile (S[0..1], V tile Vs) — v8 verbatim
  auto softpv = [&](f32x16* S, const _Float16* Vs) {
    float mx = -INFINITY;
#pragma unroll
    for (int kb = 0; kb < 2; ++kb)
#pragma unroll
      for (int r = 0; r < 16; ++r) mx = fmaxf(mx, S[kb][r]);
    mx = fmaxf(mx, __shfl_xor(mx, 32));

    // defer-max: only rescale when the max grew enough to matter
    if (__any(mx > m_i + DEFER_THR)) {
      float m_new = fmaxf(m_i, mx);
      float alpha = __builtin_amdgcn_exp2f(m_i - m_new);
      l_i *= alpha;
#pragma unroll
      for (int nt = 0; nt < 2; ++nt)
#pragma unroll
        for (int r = 0; r < 16; ++r) O[nt][r] *= alpha;
      m_i = m_new;
    }

    float s = 0.f;
#pragma unroll
    for (int kb = 0; kb < 2; ++kb)
#pragma unroll
      for (int r = 0; r < 16; ++r) {
        float p = __builtin_amdgcn_exp2f(S[kb][r] - m_i);
        S[kb][r] = p;
        s += p;
      }
    s += __shfl_xor(s, 32);
    l_i += s;

#pragma unroll
    for (int kb = 0; kb < 2; ++kb) {
      unsigned pu[8];
#pragma unroll
      for (int i = 0; i < 8; ++i) {
        f16x2 t2;
        t2[0] = (_Float16)S[kb][2 * i];
        t2[1] = (_Float16)S[kb][2 * i + 1];
        pu[i] = __builtin_bit_cast(unsigned, t2);
      }
#pragma unroll
      for (int c = 0; c < 2; ++c) {
        unsigned u0 = pu[4 * c + 0], u1 = pu[4 * c + 1];
        unsigned u2 = pu[4 * c + 2], u3 = pu[4 * c + 3];
        asm("v_permlane32_swap_b32 %0, %1" : "+v"(u0), "+v"(u2));
        asm("v_permlane32_swap_b32 %0, %1" : "+v"(u1), "+v"(u3));
        union { unsigned u[4]; f16x8 v; } pb;
        pb.u[0] = u0; pb.u[1] = u1; pb.u[2] = u2; pb.u[3] = u3;
        const int kb2 = kb * 2 + c;            // 16-key granule 0..3
        f16x8 av[2];
#pragma unroll
        for (int nt = 0; nt < 2; ++nt) {
          int dim = nt * 32 + l31;
          int pc = ((kb2 * 2 + half) ^ (dim & 7)) * 8;
          av[nt] = *(const f16x8*)&Vs[dim * 64 + pc];
        }
#pragma unroll
        for (int nt = 0; nt < 2; ++nt)
          O[nt] = __builtin_amdgcn_mfma_f32_32x32x16_f16(av[nt], pb.v, O[nt], 0, 0, 0);
      }
    }
  };

  f32x16 Sa[2], Sb[2];

  // ---- prologue: load tile 0; step 0 (qk tile 0 -> Sb, prefetch tile 1) ----
  dma_k(0, K0s);
  dma_v(0, V0s);
  __syncthreads();
  dma_k(64, K1s);
  dma_v(64, V1s);
  qk(K0s, Sb);

  // ---- steps 1..28: 7 macro-iterations of 4 static steps ----
  // step 4j+1: dK->K0 (tile 4j+2), dV->V2; qk(K1=tile 4j+1)->Sa; softpv(Sb, V0=tile 4j)
  // step 4j+2: dK->K1, dV->V3; qk(K0)->Sb; softpv(Sa, V1)
  // step 4j+3: dK->K0, dV->V0; qk(K1)->Sa; softpv(Sb, V2)
  // step 4j+4: dK->K1, dV->V1; qk(K0)->Sb; softpv(Sa, V3)
  for (int j = 0; j < 7; ++j) {
    const int t = j * 256 + 64;        // global key offset of tile 4j+1
    __syncthreads();
    dma_k(t + 64, K0s);  dma_v(t + 64, V2s);
    qk(K1s, Sa);  softpv(Sb, V0s);
    __syncthreads();
    dma_k(t + 128, K1s); dma_v(t + 128, V3s);
    qk(K0s, Sb);  softpv(Sa, V1s);
    __syncthreads();
    dma_k(t + 192, K0s); dma_v(t + 192, V0s);
    qk(K1s, Sa);  softpv(Sb, V2s);
    __syncthreads();
    dma_k(t + 256, K1s); dma_v(t + 256, V1s);
    qk(K0s, Sb);  softpv(Sa, V3s);
  }

  // ---- step 29: dK(1920 -> K0 = tile 30), dV -> V2; qk(K1 = tile 29); softpv(tile 28, V0)
  __syncthreads();
  dma_k(1920, K0s); dma_v(1920, V2s);
  qk(K1s, Sa);  softpv(Sb, V0s);
  // ---- step 30: dK(1984 -> K1 = tile 31), dV -> V3; qk(K0 = tile 30); softpv(tile 29, V1)
  __syncthreads();
  dma_k(1984, K1s); dma_v(1984, V3s);
  qk(K0s, Sb);  softpv(Sa, V1s);
  // ---- step 31: qk(K1 = tile 31); softpv(tile 30, V2); drain softpv(tile 31, V3)
  __syncthreads();
  qk(K1s, Sa);  softpv(Sb, V2s);
  softpv(Sa, V3s);

  float inv = 1.f / l_i;
  int qrow = qt0 + w * 32 + l31;
#pragma unroll
  for (int nt = 0; nt < 2; ++nt)
#pragma unroll
    for (int rg = 0; rg < 4; ++rg) {
      f16x4 o4;
#pragma unroll
      for (int i = 0; i < 4; ++i) o4[i] = (_Float16)(O[nt][rg * 4 + i] * inv);
      int dim = nt * 32 + rg * 8 + half * 4;
      *(f16x4*)&y[((size_t)b * LQ + qrow) * EQ + h * 64 + dim] = o4;
    }
}

// ---------------------------------------------------------------------------
extern "C" void kernel_launch(void* const* d_in, const int* in_sizes, int n_in,
                              void* d_out, int out_size, void* d_ws, size_t ws_size,
                              hipStream_t stream) {
  const float* xt = (const float*)d_in[0];
  const float* xs = (const float*)d_in[1];
  const float* Wt = (const float*)d_in[2];
  const float* bt = (const float*)d_in[3];
  const float* Ws = (const float*)d_in[4];
  const float* bs = (const float*)d_in[5];
  const float* Wc = (const float*)d_in[6];
  const float* bc = (const float*)d_in[7];
  const float* lam_ts = (const float*)d_in[8];
  const float* lam_st = (const float*)d_in[9];
  const float* lam_ss = (const float*)d_in[10];
  float* out = (float*)d_out;

  _Float16* w16 = (_Float16*)d_ws;
  _Float16* xt16 = w16;                       // 4,194,304
  _Float16* xs16 = xt16 + 4194304;            // 4,194,304
  _Float16* WtT  = xs16 + 4194304;            // 3,145,728
  _Float16* WsT  = WtT + 3145728;             // 2,097,152
  _Float16* WcT  = WsT + 2097152;             // 1,048,576
  _Float16* qcat = WcT + 1048576;             // 8,388,608  [bh][l][128] = [qt|qs]
  _Float16* kcat = qcat + 8388608;            // 8,388,608  [bh][l][128] = [kt|ks]
  _Float16* vbufT = kcat + 8388608;           // 4,194,304  [bh][dim][l]
  _Float16* ybuf = vbufT + 4194304;           // 4,194,304  [b*l][1024]

  prep<<<7168, 256, 0, stream>>>(xt, xs, Wt, Ws, Wc, xt16, xs16, WtT, WsT, WcT);
  proj_gemm<<<dim3(16, 80), 256, 0, stream>>>(
      xt16, xs16, WtT, WsT, bt, bs, qcat, kcat, vbufT);
  flash_attn_mfma<<<dim3(16, 32), 256, 0, stream>>>(
      qcat, kcat, vbufT, ybuf, lam_ts, lam_st, lam_ss);
  cproj_gemm<<<dim3(16, 32), 256, 0, stream>>>(ybuf, WcT, bc, out);
}